// Round 1
// baseline (300.095 us; speedup 1.0000x reference)
//
#include <hip/hip_runtime.h>
#include <cstdint>
#include <cstddef>

#define D_IN   128
#define O_DIM  128
#define KCAT   384
#define NPB    16      // nodes per block in aggregate kernel
#define BM     128
#define BK     32

typedef __attribute__((ext_vector_type(8))) short bf16x8;
typedef __attribute__((ext_vector_type(4))) float f32x4;

// f32 -> bf16 (round to nearest even), bit-level (inputs are finite)
static __device__ __forceinline__ unsigned short f2bf(float f) {
    unsigned int u = __builtin_bit_cast(unsigned int, f);
    unsigned int lsb = (u >> 16) & 1u;
    u += 0x7fffu + lsb;
    return (unsigned short)(u >> 16);
}

// async global -> LDS, 16B per lane; lds base must be wave-uniform,
// HW writes lane i at base + i*16
static __device__ __forceinline__ void async16(const unsigned short* g, void* lds_wave_base) {
    __builtin_amdgcn_global_load_lds(
        (const __attribute__((address_space(1))) void*)g,
        (__attribute__((address_space(3))) void*)lds_wave_base,
        16, 0, 0);
}

// ---------------- Kernel 0: V[o][k] = concat(Wg,Wl,Ws)[o][k] in bf16 ----------------
__global__ void build_V(const float* __restrict__ Wg, const float* __restrict__ Wl,
                        const float* __restrict__ Ws, unsigned short* __restrict__ V) {
    const int o = blockIdx.x;     // 128 blocks
    const int k = threadIdx.x;    // 384 threads
    float v;
    if (k < 128)      v = Wg[o * 128 + k];
    else if (k < 256) v = Wl[o * 128 + (k - 128)];
    else              v = Ws[o * 128 + (k - 256)];
    V[o * KCAT + k] = f2bf(v);
}

// ---------------- Kernel 1: aggregation + build U[n][0:384] bf16 ----------------
// U[n,0:128]=x[n], U[n,128:256]=mask*neigh_mean[n], U[n,256:384]=mask*x[n]
__global__ void aggregate(const float* __restrict__ x, const int* __restrict__ src,
                          const int* __restrict__ dst, const int* __restrict__ deg,
                          unsigned short* __restrict__ U, int N, int E) {
    __shared__ int sdeg[NPB];
    __shared__ int sstart[NPB];
    const int t      = threadIdx.x;          // 256 threads
    const int lane_f = t & 127;              // feature lane
    const int half   = t >> 7;               // 0 or 1: which node of the pair
    const int base   = blockIdx.x * NPB;

    if (t < NPB) {
        int n = base + t;
        sdeg[t] = (n < N) ? deg[n] : 0;
    }
    // lower_bound(dst, base): dst is sorted ascending (grouped edges).
    // All threads do it redundantly (same-address broadcast loads).
    int lo = 0, hi = E;
    while (lo < hi) {
        int mid = (lo + hi) >> 1;
        if (dst[mid] < base) lo = mid + 1; else hi = mid;
    }
    if (t == 0) {
        int run = lo;
        for (int i = 0; i < NPB; ++i) { sstart[i] = run; run += sdeg[i]; }
    }
    __syncthreads();

    for (int r = 0; r < NPB / 2; ++r) {
        int i = r * 2 + half;
        int n = base + i;
        if (n >= N) continue;
        int s = sstart[i], d = sdeg[i];
        float acc = 0.f;
        for (int e = 0; e < d; ++e) {
            int sn = src[s + e];
            acc += x[(size_t)sn * D_IN + lane_f];
        }
        float xv   = x[(size_t)n * D_IN + lane_f];
        float mean = (d > 0) ? acc * (1.0f / (float)d) : 0.f;
        size_t ub = (size_t)n * KCAT;
        U[ub + lane_f]       = f2bf(xv);
        U[ub + 128 + lane_f] = f2bf(mean);
        U[ub + 256 + lane_f] = (d > 0) ? f2bf(xv) : (unsigned short)0;
    }
}

// ---------------- Kernel 2: out = elu(U @ V^T + b), MFMA bf16 ----------------
// Tile: 128 rows x 128 cols per block, 4 waves each own a 64x64 quadrant
// (4x4 grid of 16x16x32 MFMAs), K-loop 384/32 = 12 steps.
__global__ __launch_bounds__(256)
void gemm_epilogue(const unsigned short* __restrict__ U, const unsigned short* __restrict__ V,
                   const float* __restrict__ bias, float* __restrict__ out, int N) {
    __shared__ __align__(16) unsigned short As[BM * BK];    // [row][32k], 64B rows
    __shared__ __align__(16) unsigned short Bs[O_DIM * BK]; // [o][32k]
    const int t    = threadIdx.x;
    const int w    = t >> 6;          // wave 0..3
    const int lane = t & 63;
    const int row0 = blockIdx.x * BM;
    const int wrow = (w >> 1) * 64;
    const int wcol = (w & 1) * 64;
    const int quad = lane >> 4;

    f32x4 acc[4][4];
#pragma unroll
    for (int i = 0; i < 4; ++i)
#pragma unroll
        for (int j = 0; j < 4; ++j)
            acc[i][j] = (f32x4){0.f, 0.f, 0.f, 0.f};

    for (int k0 = 0; k0 < KCAT; k0 += BK) {
        // stage A (8KB) and B (8KB): 512 chunks of 16B each, 2 iters x 256 threads
#pragma unroll
        for (int it = 0; it < 2; ++it) {
            int f   = it * 256 + t;
            int row = f >> 2;          // 0..127
            int c4  = f & 3;           // 16B chunk within the 64B row segment
            int grow = row0 + row; if (grow > N - 1) grow = N - 1;   // clamp tail
            const unsigned short* ga = U + (size_t)grow * KCAT + k0 + c4 * 8;
            const unsigned short* gb = V + (size_t)row  * KCAT + k0 + c4 * 8;
            char* la = (char*)As + (size_t)(it * 256 + w * 64) * 16;
            char* lb = (char*)Bs + (size_t)(it * 256 + w * 64) * 16;
            async16(ga, la);
            async16(gb, lb);
        }
        __syncthreads();

        bf16x8 af[4], bfr[4];
#pragma unroll
        for (int ri = 0; ri < 4; ++ri) {
            int rr = wrow + ri * 16 + (lane & 15);
            af[ri] = *(const bf16x8*)((const char*)As + rr * 64 + quad * 16);
        }
#pragma unroll
        for (int ci = 0; ci < 4; ++ci) {
            int cc = wcol + ci * 16 + (lane & 15);
            bfr[ci] = *(const bf16x8*)((const char*)Bs + cc * 64 + quad * 16);
        }
#pragma unroll
        for (int ri = 0; ri < 4; ++ri)
#pragma unroll
            for (int ci = 0; ci < 4; ++ci)
                acc[ri][ci] = __builtin_amdgcn_mfma_f32_16x16x32_bf16(af[ri], bfr[ci], acc[ri][ci], 0, 0, 0);
        __syncthreads();
    }

    // epilogue: + bias, ELU, store f32.  C/D: col=lane&15, row=quad*4+reg
#pragma unroll
    for (int ri = 0; ri < 4; ++ri) {
#pragma unroll
        for (int ci = 0; ci < 4; ++ci) {
            int col = wcol + ci * 16 + (lane & 15);
            float bv = bias[col];
#pragma unroll
            for (int reg = 0; reg < 4; ++reg) {
                int row = row0 + wrow + ri * 16 + quad * 4 + reg;
                if (row < N) {
                    float v = acc[ri][ci][reg] + bv;
                    out[(size_t)row * O_DIM + col] = (v > 0.f) ? v : expm1f(v);
                }
            }
        }
    }
}

extern "C" void kernel_launch(void* const* d_in, const int* in_sizes, int n_in,
                              void* d_out, int out_size, void* d_ws, size_t ws_size,
                              hipStream_t stream) {
    const float* x  = (const float*)d_in[0];
    const float* Wg = (const float*)d_in[1];
    const float* Wl = (const float*)d_in[2];
    const float* Ws = (const float*)d_in[3];
    const float* b  = (const float*)d_in[4];
    const int*   src = (const int*)d_in[5];
    const int*   dst = (const int*)d_in[6];
    const int*   deg = (const int*)d_in[7];
    const int E = in_sizes[5];
    const int N = in_sizes[7];
    float* out = (float*)d_out;

    unsigned short* V = (unsigned short*)d_ws;                       // 128*384*2 = 96 KB
    unsigned short* U = (unsigned short*)((char*)d_ws + 98304);      // N*384*2 = 38.4 MB

    build_V<<<dim3(O_DIM), dim3(KCAT), 0, stream>>>(Wg, Wl, Ws, V);
    aggregate<<<dim3((N + NPB - 1) / NPB), dim3(256), 0, stream>>>(x, src, dst, deg, U, N, E);
    gemm_epilogue<<<dim3((N + BM - 1) / BM), dim3(256), 0, stream>>>(U, V, b, out, N);
}

// Round 2
// 176.714 us; speedup vs baseline: 1.6982x; 1.6982x over previous
//
#include <hip/hip_runtime.h>
#include <cstdint>
#include <cstddef>

#define D_IN   128
#define O_DIM  128
#define KCAT   384
#define BM     128
#define BK     32
#define AGG_BLOCK 512
#define AGG_NPB   8

typedef __attribute__((ext_vector_type(8))) short bf16x8;
typedef __attribute__((ext_vector_type(4))) float f32x4;

// f32 -> bf16 (round to nearest even), bit-level (inputs are finite)
static __device__ __forceinline__ unsigned short f2bf(float f) {
    unsigned int u = __builtin_bit_cast(unsigned int, f);
    unsigned int lsb = (u >> 16) & 1u;
    u += 0x7fffu + lsb;
    return (unsigned short)(u >> 16);
}

static __device__ __forceinline__ void f4acc(float4& a, const float4& b) {
    a.x += b.x; a.y += b.y; a.z += b.z; a.w += b.w;
}

// async global -> LDS, 16B per lane; lds base must be wave-uniform,
// HW writes lane i at base + i*16
static __device__ __forceinline__ void async16(const unsigned short* g, void* lds_wave_base) {
    __builtin_amdgcn_global_load_lds(
        (const __attribute__((address_space(1))) void*)g,
        (__attribute__((address_space(3))) void*)lds_wave_base,
        16, 0, 0);
}

// ---------------- Kernel 0: V[o][k] = concat(Wg,Wl,Ws)[o][k] in bf16 ----------------
__global__ void build_V(const float* __restrict__ Wg, const float* __restrict__ Wl,
                        const float* __restrict__ Ws, unsigned short* __restrict__ V) {
    const int o = blockIdx.x;     // 128 blocks
    const int k = threadIdx.x;    // 384 threads
    float v;
    if (k < 128)      v = Wg[o * 128 + k];
    else if (k < 256) v = Wl[o * 128 + (k - 128)];
    else              v = Ws[o * 128 + (k - 256)];
    V[o * KCAT + k] = f2bf(v);
}

// ---------------- Kernel 1: aggregation + build U[n][0:384] bf16 ----------------
// One WAVE per node. lane = parity(p=lane>>5) x float4-col(c=lane&31).
// Edge loop unrolled x4 over parity stride 2 => 8 independent 512B row loads
// in flight per wave. Cross-parity reduce via shfl_xor(32).
// U[n,0:128]=x[n], U[n,128:256]=mask*neigh_mean[n], U[n,256:384]=mask*x[n]
__global__ __launch_bounds__(AGG_BLOCK)
void aggregate(const float* __restrict__ x, const int* __restrict__ src,
               const int* __restrict__ dst, const int* __restrict__ deg,
               unsigned short* __restrict__ U, int N, int E) {
    __shared__ int sdeg[AGG_NPB];
    __shared__ int sstart[AGG_NPB];
    const int t    = threadIdx.x;           // 512 threads = 8 waves
    const int wv   = t >> 6;                // wave id = node slot
    const int lane = t & 63;
    const int c    = lane & 31;             // float4 column (32 x float4 = 128 floats)
    const int p    = lane >> 5;             // edge parity
    const int base = blockIdx.x * AGG_NPB;

    if (t < AGG_NPB) {
        int n = base + t;
        sdeg[t] = (n < N) ? deg[n] : 0;
    }
    // lower_bound(dst, base): dst sorted ascending (edges grouped by dst).
    // Redundant across threads (broadcast loads) — one chain per block.
    int lo = 0, hi = E;
    while (lo < hi) {
        int mid = (lo + hi) >> 1;
        if (dst[mid] < base) lo = mid + 1; else hi = mid;
    }
    __syncthreads();
    if (t == 0) {
        int run = lo;
        for (int i = 0; i < AGG_NPB; ++i) { sstart[i] = run; run += sdeg[i]; }
    }
    __syncthreads();

    const int n = base + wv;
    if (n >= N) return;
    const int s = sstart[wv];
    const int d = sdeg[wv];
    const float4* x4 = (const float4*)x;

    float4 a0 = {0,0,0,0}, a1 = {0,0,0,0}, a2 = {0,0,0,0}, a3 = {0,0,0,0};
    int e = p;
    for (; e + 6 < d; e += 8) {
        int i0 = src[s + e];
        int i1 = src[s + e + 2];
        int i2 = src[s + e + 4];
        int i3 = src[s + e + 6];
        float4 r0 = x4[(size_t)i0 * 32 + c];
        float4 r1 = x4[(size_t)i1 * 32 + c];
        float4 r2 = x4[(size_t)i2 * 32 + c];
        float4 r3 = x4[(size_t)i3 * 32 + c];
        f4acc(a0, r0); f4acc(a1, r1); f4acc(a2, r2); f4acc(a3, r3);
    }
    for (; e < d; e += 2) {
        float4 r = x4[(size_t)src[s + e] * 32 + c];
        f4acc(a0, r);
    }
    f4acc(a0, a1); f4acc(a2, a3); f4acc(a0, a2);
    a0.x += __shfl_xor(a0.x, 32, 64);
    a0.y += __shfl_xor(a0.y, 32, 64);
    a0.z += __shfl_xor(a0.z, 32, 64);
    a0.w += __shfl_xor(a0.w, 32, 64);

    float4 xv = x4[(size_t)n * 32 + c];
    if (p == 0) {
        float inv = (d > 0) ? 1.0f / (float)d : 0.0f;
        size_t ub = (size_t)n * KCAT;
        ushort4 sx; sx.x = f2bf(xv.x); sx.y = f2bf(xv.y); sx.z = f2bf(xv.z); sx.w = f2bf(xv.w);
        ushort4 sm; sm.x = f2bf(a0.x * inv); sm.y = f2bf(a0.y * inv);
                    sm.z = f2bf(a0.z * inv); sm.w = f2bf(a0.w * inv);
        ushort4 sz;
        if (d > 0) sz = sx; else { sz.x = 0; sz.y = 0; sz.z = 0; sz.w = 0; }
        *(ushort4*)(U + ub + (size_t)c * 4)       = sx;
        *(ushort4*)(U + ub + 128 + (size_t)c * 4) = sm;
        *(ushort4*)(U + ub + 256 + (size_t)c * 4) = sz;
    }
}

// ---------------- Kernel 2: out = elu(U @ V^T + b), MFMA bf16 ----------------
// Tile: 128 rows x 128 cols per block, 4 waves each own a 64x64 quadrant
// (4x4 grid of 16x16x32 MFMAs), K-loop 384/32 = 12 steps.
__global__ __launch_bounds__(256)
void gemm_epilogue(const unsigned short* __restrict__ U, const unsigned short* __restrict__ V,
                   const float* __restrict__ bias, float* __restrict__ out, int N) {
    __shared__ __align__(16) unsigned short As[BM * BK];    // [row][32k], 64B rows
    __shared__ __align__(16) unsigned short Bs[O_DIM * BK]; // [o][32k]
    const int t    = threadIdx.x;
    const int w    = t >> 6;          // wave 0..3
    const int lane = t & 63;
    const int row0 = blockIdx.x * BM;
    const int wrow = (w >> 1) * 64;
    const int wcol = (w & 1) * 64;
    const int quad = lane >> 4;

    f32x4 acc[4][4];
#pragma unroll
    for (int i = 0; i < 4; ++i)
#pragma unroll
        for (int j = 0; j < 4; ++j)
            acc[i][j] = (f32x4){0.f, 0.f, 0.f, 0.f};

    for (int k0 = 0; k0 < KCAT; k0 += BK) {
        // stage A (8KB) and B (8KB): 512 chunks of 16B each, 2 iters x 256 threads
#pragma unroll
        for (int it = 0; it < 2; ++it) {
            int f   = it * 256 + t;
            int row = f >> 2;          // 0..127
            int c4  = f & 3;           // 16B chunk within the 64B row segment
            int grow = row0 + row; if (grow > N - 1) grow = N - 1;   // clamp tail
            const unsigned short* ga = U + (size_t)grow * KCAT + k0 + c4 * 8;
            const unsigned short* gb = V + (size_t)row  * KCAT + k0 + c4 * 8;
            char* la = (char*)As + (size_t)(it * 256 + w * 64) * 16;
            char* lb = (char*)Bs + (size_t)(it * 256 + w * 64) * 16;
            async16(ga, la);
            async16(gb, lb);
        }
        __syncthreads();

        bf16x8 af[4], bfr[4];
#pragma unroll
        for (int ri = 0; ri < 4; ++ri) {
            int rr = wrow + ri * 16 + (lane & 15);
            af[ri] = *(const bf16x8*)((const char*)As + rr * 64 + quad * 16);
        }
#pragma unroll
        for (int ci = 0; ci < 4; ++ci) {
            int cc = wcol + ci * 16 + (lane & 15);
            bfr[ci] = *(const bf16x8*)((const char*)Bs + cc * 64 + quad * 16);
        }
#pragma unroll
        for (int ri = 0; ri < 4; ++ri)
#pragma unroll
            for (int ci = 0; ci < 4; ++ci)
                acc[ri][ci] = __builtin_amdgcn_mfma_f32_16x16x32_bf16(af[ri], bfr[ci], acc[ri][ci], 0, 0, 0);
        __syncthreads();
    }

    // epilogue: + bias, ELU, store f32.  C/D: col=lane&15, row=quad*4+reg
#pragma unroll
    for (int ri = 0; ri < 4; ++ri) {
#pragma unroll
        for (int ci = 0; ci < 4; ++ci) {
            int col = wcol + ci * 16 + (lane & 15);
            float bv = bias[col];
#pragma unroll
            for (int reg = 0; reg < 4; ++reg) {
                int row = row0 + wrow + ri * 16 + quad * 4 + reg;
                if (row < N) {
                    float v = acc[ri][ci][reg] + bv;
                    out[(size_t)row * O_DIM + col] = (v > 0.f) ? v : expm1f(v);
                }
            }
        }
    }
}

extern "C" void kernel_launch(void* const* d_in, const int* in_sizes, int n_in,
                              void* d_out, int out_size, void* d_ws, size_t ws_size,
                              hipStream_t stream) {
    const float* x  = (const float*)d_in[0];
    const float* Wg = (const float*)d_in[1];
    const float* Wl = (const float*)d_in[2];
    const float* Ws = (const float*)d_in[3];
    const float* b  = (const float*)d_in[4];
    const int*   src = (const int*)d_in[5];
    const int*   dst = (const int*)d_in[6];
    const int*   deg = (const int*)d_in[7];
    const int E = in_sizes[5];
    const int N = in_sizes[7];
    float* out = (float*)d_out;

    unsigned short* V = (unsigned short*)d_ws;                       // 128*384*2 = 96 KB
    unsigned short* U = (unsigned short*)((char*)d_ws + 98304);      // N*384*2 = 38.4 MB

    build_V<<<dim3(O_DIM), dim3(KCAT), 0, stream>>>(Wg, Wl, Ws, V);
    aggregate<<<dim3((N + AGG_NPB - 1) / AGG_NPB), dim3(AGG_BLOCK), 0, stream>>>(x, src, dst, deg, U, N, E);
    gemm_epilogue<<<dim3((N + BM - 1) / BM), dim3(256), 0, stream>>>(U, V, b, out, N);
}

// Round 3
// 159.403 us; speedup vs baseline: 1.8826x; 1.1086x over previous
//
#include <hip/hip_runtime.h>
#include <cstdint>
#include <cstddef>

#define D_IN   128
#define O_DIM  128
#define KCAT   384
#define BM     64
#define BK     32
#define AGG_BLOCK 512
#define AGG_NPB   8

typedef __attribute__((ext_vector_type(8))) short bf16x8;
typedef __attribute__((ext_vector_type(4))) float f32x4;

// f32 -> bf16 (round to nearest even), bit-level (inputs are finite)
static __device__ __forceinline__ unsigned short f2bf(float f) {
    unsigned int u = __builtin_bit_cast(unsigned int, f);
    unsigned int lsb = (u >> 16) & 1u;
    u += 0x7fffu + lsb;
    return (unsigned short)(u >> 16);
}
static __device__ __forceinline__ float bfhi(unsigned int u) {  // high bf16 -> f32
    return __builtin_bit_cast(float, u & 0xFFFF0000u);
}
static __device__ __forceinline__ float bflo(unsigned int u) {  // low bf16 -> f32
    return __builtin_bit_cast(float, u << 16);
}

// async global -> LDS, 16B per lane; lds base must be wave-uniform,
// HW writes lane i at base + i*16
static __device__ __forceinline__ void async16(const unsigned short* g, void* lds_wave_base) {
    __builtin_amdgcn_global_load_lds(
        (const __attribute__((address_space(1))) void*)g,
        (__attribute__((address_space(3))) void*)lds_wave_base,
        16, 0, 0);
}

// ---------------- Kernel 0: V[o][k] = concat(Wg,Wl,Ws)[o][k] in bf16 ----------------
__global__ void build_V(const float* __restrict__ Wg, const float* __restrict__ Wl,
                        const float* __restrict__ Ws, unsigned short* __restrict__ V) {
    const int o = blockIdx.x;     // 128 blocks
    const int k = threadIdx.x;    // 384 threads
    float v;
    if (k < 128)      v = Wg[o * 128 + k];
    else if (k < 256) v = Wl[o * 128 + (k - 128)];
    else              v = Ws[o * 128 + (k - 256)];
    V[o * KCAT + k] = f2bf(v);
}

// ---------------- Kernel 0b: xb = bf16(x), zb = (deg>0) ? xb : 0 ----------------
// one thread per 8 elements (16B out, 32B in)
__global__ __launch_bounds__(256)
void convert_x(const float* __restrict__ x, const int* __restrict__ deg,
               unsigned short* __restrict__ xb, unsigned short* __restrict__ zb, int total8) {
    int gid = blockIdx.x * 256 + threadIdx.x;
    if (gid >= total8) return;
    int n = gid >> 4;                       // 16 threads per 128-elem row
    const float4* px = (const float4*)x + (size_t)gid * 2;
    float4 a = px[0], bq = px[1];
    uint4 u;
    u.x = (unsigned)f2bf(a.x)  | ((unsigned)f2bf(a.y)  << 16);
    u.y = (unsigned)f2bf(a.z)  | ((unsigned)f2bf(a.w)  << 16);
    u.z = (unsigned)f2bf(bq.x) | ((unsigned)f2bf(bq.y) << 16);
    u.w = (unsigned)f2bf(bq.z) | ((unsigned)f2bf(bq.w) << 16);
    ((uint4*)xb)[gid] = u;
    uint4 z = u;
    if (deg[n] == 0) { z.x = 0; z.y = 0; z.z = 0; z.w = 0; }
    ((uint4*)zb)[gid] = z;
}

// ---------------- Kernel 1: M[n] = mask * mean_{e} xb[src[e]]  (bf16) ----------------
// One WAVE per node. lane = parity(p=lane>>4, 4 parities) x col(c=lane&15, 16B each).
// All <=32 edge indices loaded in ONE shot by lanes 0..31; row indices then come
// from __shfl -> no src->row dependent chain. 16 row-loads in flight per wave.
__global__ __launch_bounds__(AGG_BLOCK)
void aggregate(const unsigned short* __restrict__ xb, const int* __restrict__ src,
               const int* __restrict__ dst, const int* __restrict__ deg,
               unsigned short* __restrict__ M, int N, int E) {
    __shared__ int sdeg[AGG_NPB];
    __shared__ int sstart[AGG_NPB];
    const int t    = threadIdx.x;           // 512 threads = 8 waves
    const int wv   = t >> 6;                // wave id = node slot
    const int lane = t & 63;
    const int c    = lane & 15;             // 16B column (16 x 16B = 256B row)
    const int p    = lane >> 4;             // edge parity 0..3
    const int base = blockIdx.x * AGG_NPB;

    if (t < AGG_NPB) {
        int n = base + t;
        sdeg[t] = (n < N) ? deg[n] : 0;
    }
    // lower_bound(dst, base): dst sorted ascending (edges grouped by dst).
    int lo = 0, hi = E;
    while (lo < hi) {
        int mid = (lo + hi) >> 1;
        if (dst[mid] < base) lo = mid + 1; else hi = mid;
    }
    __syncthreads();
    if (t == 0) {
        int run = lo;
        for (int i = 0; i < AGG_NPB; ++i) { sstart[i] = run; run += sdeg[i]; }
    }
    __syncthreads();

    const int n = base + wv;
    if (n >= N) return;
    const int s = sstart[wv];
    const int d = sdeg[wv];

    int idx = 0;
    if (lane < d) idx = src[s + lane];      // d <= 32: one coalesced shot

    float a[8] = {0,0,0,0,0,0,0,0};
    float b[8] = {0,0,0,0,0,0,0,0};
    const uint4* x4 = (const uint4*)xb;     // 16B chunks; row = 16 chunks

    for (int g = 0; g * 16 < d; ++g) {
        int e0 = g * 16 + p;                // this parity handles e0, e0+4, e0+8, e0+12
        int r0 = __shfl(idx, e0);
        int r1 = __shfl(idx, e0 + 4);
        int r2 = __shfl(idx, e0 + 8);
        int r3 = __shfl(idx, e0 + 12);
        uint4 v0 = x4[(size_t)r0 * 16 + c];
        uint4 v1 = x4[(size_t)r1 * 16 + c];
        uint4 v2 = x4[(size_t)r2 * 16 + c];
        uint4 v3 = x4[(size_t)r3 * 16 + c];
        if (e0 < d) {
            a[0]+=bflo(v0.x); a[1]+=bfhi(v0.x); a[2]+=bflo(v0.y); a[3]+=bfhi(v0.y);
            a[4]+=bflo(v0.z); a[5]+=bfhi(v0.z); a[6]+=bflo(v0.w); a[7]+=bfhi(v0.w);
        }
        if (e0 + 4 < d) {
            b[0]+=bflo(v1.x); b[1]+=bfhi(v1.x); b[2]+=bflo(v1.y); b[3]+=bfhi(v1.y);
            b[4]+=bflo(v1.z); b[5]+=bfhi(v1.z); b[6]+=bflo(v1.w); b[7]+=bfhi(v1.w);
        }
        if (e0 + 8 < d) {
            a[0]+=bflo(v2.x); a[1]+=bfhi(v2.x); a[2]+=bflo(v2.y); a[3]+=bfhi(v2.y);
            a[4]+=bflo(v2.z); a[5]+=bfhi(v2.z); a[6]+=bflo(v2.w); a[7]+=bfhi(v2.w);
        }
        if (e0 + 12 < d) {
            b[0]+=bflo(v3.x); b[1]+=bfhi(v3.x); b[2]+=bflo(v3.y); b[3]+=bfhi(v3.y);
            b[4]+=bflo(v3.z); b[5]+=bfhi(v3.z); b[6]+=bflo(v3.w); b[7]+=bfhi(v3.w);
        }
    }
#pragma unroll
    for (int i = 0; i < 8; ++i) a[i] += b[i];
    // reduce across the 4 parities (lanes c, c+16, c+32, c+48)
#pragma unroll
    for (int i = 0; i < 8; ++i) {
        a[i] += __shfl_xor(a[i], 16, 64);
        a[i] += __shfl_xor(a[i], 32, 64);
    }
    if (p == 0) {
        float inv = (d > 0) ? 1.0f / (float)d : 0.0f;
        uint4 u;
        u.x = (unsigned)f2bf(a[0]*inv) | ((unsigned)f2bf(a[1]*inv) << 16);
        u.y = (unsigned)f2bf(a[2]*inv) | ((unsigned)f2bf(a[3]*inv) << 16);
        u.z = (unsigned)f2bf(a[4]*inv) | ((unsigned)f2bf(a[5]*inv) << 16);
        u.w = (unsigned)f2bf(a[6]*inv) | ((unsigned)f2bf(a[7]*inv) << 16);
        ((uint4*)M)[(size_t)n * 16 + c] = u;   // always write (ws is poisoned)
    }
}

// ---------------- Kernel 2: out = elu([xb|M|zb] @ V^T + b), MFMA bf16 ----------------
// Tile: 64 rows x 128 cols per block (782 blocks ~3/CU), 4 waves each own a
// 64x32 column slice (4x2 grid of 16x16x32 MFMAs), K-loop 384/32 = 12 steps.
__global__ __launch_bounds__(256)
void gemm_epilogue(const unsigned short* __restrict__ xb, const unsigned short* __restrict__ Mm,
                   const unsigned short* __restrict__ zb, const unsigned short* __restrict__ V,
                   const float* __restrict__ bias, float* __restrict__ out, int N) {
    __shared__ __align__(16) unsigned short As[BM * BK];    // 4 KB, [row][32k] 64B rows
    __shared__ __align__(16) unsigned short Bs[O_DIM * BK]; // 8 KB
    const int t    = threadIdx.x;
    const int w    = t >> 6;          // wave 0..3
    const int lane = t & 63;
    const int row0 = blockIdx.x * BM;
    const int wcol = w * 32;
    const int quad = lane >> 4;

    f32x4 acc[4][2];
#pragma unroll
    for (int i = 0; i < 4; ++i)
#pragma unroll
        for (int j = 0; j < 2; ++j)
            acc[i][j] = (f32x4){0.f, 0.f, 0.f, 0.f};

    for (int k0 = 0; k0 < KCAT; k0 += BK) {
        // pick A-source per k-range: [xb | M | zb], each N x 128
        const unsigned short* Asrc; int kloc;
        if (k0 < 128)      { Asrc = xb; kloc = k0; }
        else if (k0 < 256) { Asrc = Mm; kloc = k0 - 128; }
        else               { Asrc = zb; kloc = k0 - 256; }

        // stage A (4KB): 256 threads x 16B. row = t>>2 (0..63), c4 = t&3
        {
            int row = t >> 2, c4 = t & 3;
            int grow = row0 + row; if (grow > N - 1) grow = N - 1;   // clamp tail
            async16(Asrc + (size_t)grow * 128 + kloc + c4 * 8,
                    (char*)As + (size_t)(w * 64) * 16);
        }
        // stage B (8KB): 2 x 256 threads x 16B
#pragma unroll
        for (int it = 0; it < 2; ++it) {
            int f = it * 256 + t;
            int row = f >> 2, c4 = f & 3;     // row 0..127 of V
            async16(V + (size_t)row * KCAT + k0 + c4 * 8,
                    (char*)Bs + (size_t)(it * 256 + w * 64) * 16);
        }
        __syncthreads();

        bf16x8 af[4], bfr[2];
#pragma unroll
        for (int ri = 0; ri < 4; ++ri) {
            int rr = ri * 16 + (lane & 15);
            af[ri] = *(const bf16x8*)((const char*)As + rr * 64 + quad * 16);
        }
#pragma unroll
        for (int ci = 0; ci < 2; ++ci) {
            int cc = wcol + ci * 16 + (lane & 15);
            bfr[ci] = *(const bf16x8*)((const char*)Bs + cc * 64 + quad * 16);
        }
#pragma unroll
        for (int ri = 0; ri < 4; ++ri)
#pragma unroll
            for (int ci = 0; ci < 2; ++ci)
                acc[ri][ci] = __builtin_amdgcn_mfma_f32_16x16x32_bf16(af[ri], bfr[ci], acc[ri][ci], 0, 0, 0);
        __syncthreads();
    }

    // epilogue: + bias, ELU, store f32.  C/D: col=lane&15, row=quad*4+reg
#pragma unroll
    for (int ri = 0; ri < 4; ++ri) {
#pragma unroll
        for (int ci = 0; ci < 2; ++ci) {
            int col = wcol + ci * 16 + (lane & 15);
            float bv = bias[col];
#pragma unroll
            for (int reg = 0; reg < 4; ++reg) {
                int row = row0 + ri * 16 + quad * 4 + reg;
                if (row < N) {
                    float v = acc[ri][ci][reg] + bv;
                    out[(size_t)row * O_DIM + col] = (v > 0.f) ? v : expm1f(v);
                }
            }
        }
    }
}

extern "C" void kernel_launch(void* const* d_in, const int* in_sizes, int n_in,
                              void* d_out, int out_size, void* d_ws, size_t ws_size,
                              hipStream_t stream) {
    const float* x  = (const float*)d_in[0];
    const float* Wg = (const float*)d_in[1];
    const float* Wl = (const float*)d_in[2];
    const float* Ws = (const float*)d_in[3];
    const float* b  = (const float*)d_in[4];
    const int*   src = (const int*)d_in[5];
    const int*   dst = (const int*)d_in[6];
    const int*   deg = (const int*)d_in[7];
    const int E = in_sizes[5];
    const int N = in_sizes[7];
    float* out = (float*)d_out;

    const size_t NB = (size_t)N * 128 * 2;                    // 12.8 MB per matrix
    unsigned short* V  = (unsigned short*)d_ws;               // 96 KB
    unsigned short* xb = (unsigned short*)((char*)d_ws + 98304);
    unsigned short* Mm = (unsigned short*)((char*)d_ws + 98304 + NB);
    unsigned short* zb = (unsigned short*)((char*)d_ws + 98304 + 2 * NB);

    build_V<<<dim3(O_DIM), dim3(KCAT), 0, stream>>>(Wg, Wl, Ws, V);
    int total8 = N * 16;
    convert_x<<<dim3((total8 + 255) / 256), dim3(256), 0, stream>>>(x, deg, xb, zb, total8);
    aggregate<<<dim3((N + AGG_NPB - 1) / AGG_NPB), dim3(AGG_BLOCK), 0, stream>>>(xb, src, dst, deg, Mm, N, E);
    gemm_epilogue<<<dim3((N + BM - 1) / BM), dim3(256), 0, stream>>>(xb, Mm, zb, V, b, out, N);
}